// Round 7
// baseline (329.370 us; speedup 1.0000x reference)
//
#include <hip/hip_runtime.h>

#define B_ 2
#define T_ 4096
#define C_ 768
#define H_ 12
#define D_ 64

typedef __attribute__((ext_vector_type(8))) short bf16x8;
typedef __attribute__((ext_vector_type(4))) float f32x4;
typedef __attribute__((ext_vector_type(16))) float f32x16;

__device__ __forceinline__ unsigned short f2bf(float f) {
  union { float f; unsigned u; } v; v.f = f;
  unsigned r = v.u + 0x7fffu + ((v.u >> 16) & 1u);
  return (unsigned short)(r >> 16);
}

__device__ __forceinline__ float exp2_hw(float x) {
  float r;
  asm("v_exp_f32 %0, %1" : "=v"(r) : "v"(x));
  return r;
}

__device__ __forceinline__ void gll16(const void* g, void* l) {
  __builtin_amdgcn_global_load_lds((const __attribute__((address_space(1))) void*)g,
                                   (__attribute__((address_space(3))) void*)l, 16, 0, 0);
}

// ---------------- cast kernels ----------------

__global__ __launch_bounds__(256) void cast_bf16_k(const float* __restrict__ in,
                                                   unsigned short* __restrict__ out, int n4) {
  int i = blockIdx.x * 256 + threadIdx.x;
  if (i >= n4) return;
  float4 v = ((const float4*)in)[i];
  union { unsigned short s[4]; unsigned long long u; } o;
  o.s[0] = f2bf(v.x); o.s[1] = f2bf(v.y); o.s[2] = f2bf(v.z); o.s[3] = f2bf(v.w);
  ((unsigned long long*)out)[i] = o.u;
}

// in [R][C] f32 -> out [C][R] bf16, 64x64 tiles via LDS (coalesced both sides)
__global__ __launch_bounds__(256) void tpose_cast_k(const float* __restrict__ in,
                                                    unsigned short* __restrict__ out,
                                                    int R, int C) {
  __shared__ unsigned short t[64][65];
  const int c0 = blockIdx.x * 64, r0 = blockIdx.y * 64;
  const int tr = threadIdx.x >> 6, tc = threadIdx.x & 63;
#pragma unroll
  for (int i = 0; i < 16; ++i) {
    int r = i * 4 + tr;
    t[r][tc] = f2bf(in[(size_t)(r0 + r) * C + c0 + tc]);
  }
  __syncthreads();
#pragma unroll
  for (int i = 0; i < 16; ++i) {
    int c = i * 4 + tr;
    out[(size_t)(c0 + c) * R + r0 + tc] = t[tc][c];
  }
}

// ---------------- GEMM (R5 structure, unchanged) ----------------

#define QSCALE 0.1803368801111243f /* 0.125 * log2(e) */

template <int MODE>
__global__ __launch_bounds__(256) void gemm_k(const unsigned short* __restrict__ A,
                                              const unsigned short* __restrict__ Bt,
                                              int K,
                                              unsigned short* __restrict__ q_out,
                                              unsigned short* __restrict__ k_out,
                                              unsigned short* __restrict__ vt_out,
                                              float* __restrict__ f_out,
                                              const float* __restrict__ bias) {
  __shared__ short a_lds[2][128 * 32];
  __shared__ short b_lds[2][128 * 32];
  const int tid = threadIdx.x;
  const int wave = tid >> 6, lane = tid & 63;
  const int wm = wave >> 1, wn = wave & 1;
  const int lr = lane & 15, lc = lane >> 4;

  const int id = blockIdx.x;
  const int xcd = id & 7, idc = id >> 3;
  const int bx = xcd * 8 + (idc & 7);
  const int by = idc >> 3;
  const int m0 = bx * 128, n0 = by * 128;

  f32x4 acc[4][4];
  for (int mi = 0; mi < 4; ++mi)
    for (int ni = 0; ni < 4; ++ni) acc[mi][ni] = (f32x4){0.f, 0.f, 0.f, 0.f};

  const unsigned short *ap[2], *bp[2];
  int lb[2];
#pragma unroll
  for (int p = 0; p < 2; ++p) {
    int chunk = p * 256 + wave * 64 + lane;
    int r = chunk >> 2, cc = chunk & 3;
    int c = cc ^ ((r >> 1) & 3);
    ap[p] = A + (size_t)(m0 + r) * K + c * 8;
    bp[p] = Bt + (size_t)(n0 + r) * K + c * 8;
    lb[p] = (p * 256 + wave * 64) * 8;
  }

  const int nks = K >> 5;
#pragma unroll
  for (int p = 0; p < 2; ++p) {
    gll16(ap[p], &a_lds[0][lb[p]]);
    gll16(bp[p], &b_lds[0][lb[p]]);
    ap[p] += 32; bp[p] += 32;
  }

  for (int ks = 0; ks < nks; ++ks) {
    const int buf = ks & 1;
    __builtin_amdgcn_s_barrier();
    __builtin_amdgcn_sched_barrier(0);
    if (ks + 1 < nks) {
#pragma unroll
      for (int p = 0; p < 2; ++p) {
        gll16(ap[p], &a_lds[buf ^ 1][lb[p]]);
        gll16(bp[p], &b_lds[buf ^ 1][lb[p]]);
        ap[p] += 32; bp[p] += 32;
      }
      asm volatile("s_waitcnt vmcnt(4)" ::: "memory");
    } else {
      asm volatile("s_waitcnt vmcnt(0)" ::: "memory");
    }
    __builtin_amdgcn_sched_barrier(0);
    __builtin_amdgcn_s_barrier();
    __builtin_amdgcn_sched_barrier(0);

    bf16x8 af[4], bfrag[4];
#pragma unroll
    for (int mi = 0; mi < 4; ++mi) {
      int r = wm * 64 + mi * 16 + lr;
      af[mi] = *(const bf16x8*)&a_lds[buf][r * 32 + (lc ^ ((r >> 1) & 3)) * 8];
    }
#pragma unroll
    for (int ni = 0; ni < 4; ++ni) {
      int r = wn * 64 + ni * 16 + lr;
      bfrag[ni] = *(const bf16x8*)&b_lds[buf][r * 32 + (lc ^ ((r >> 1) & 3)) * 8];
    }
    __builtin_amdgcn_s_setprio(1);
#pragma unroll
    for (int mi = 0; mi < 4; ++mi)
#pragma unroll
      for (int ni = 0; ni < 4; ++ni)
        acc[mi][ni] = __builtin_amdgcn_mfma_f32_16x16x32_bf16(af[mi], bfrag[ni], acc[mi][ni], 0, 0, 0);
    __builtin_amdgcn_s_setprio(0);
  }

  if (MODE == 0) {
    const int nn0 = n0 + wn * 64 + lr;
    const int which = n0 / 768;
#pragma unroll
    for (int mi = 0; mi < 4; ++mi)
#pragma unroll
      for (int ni = 0; ni < 4; ++ni) {
        int nn = nn0 + ni * 16;
        int rem = nn - which * 768;
        int h = rem >> 6, d = rem & 63;
        int t0v = m0 + wm * 64 + mi * 16 + lc * 4;
        int b = t0v >> 12, t = t0v & (T_ - 1);
        size_t bh = (size_t)(b * H_ + h);
        if (which == 2) {
          unsigned u0, u1;
          asm("v_cvt_pk_bf16_f32 %0, %1, %2" : "=v"(u0) : "v"(acc[mi][ni][0]), "v"(acc[mi][ni][1]));
          asm("v_cvt_pk_bf16_f32 %0, %1, %2" : "=v"(u1) : "v"(acc[mi][ni][2]), "v"(acc[mi][ni][3]));
          uint2 u = {u0, u1};
          *(uint2*)&vt_out[(bh * D_ + d) * T_ + t] = u;
        } else {
#pragma unroll
          for (int r = 0; r < 4; ++r) {
            float av = acc[mi][ni][r];
            if (which == 0) av *= QSCALE;
            unsigned short val = f2bf(av);
            if (which == 0) q_out[(bh * T_ + t + r) * D_ + d] = val;
            else            k_out[(bh * T_ + t + r) * D_ + d] = val;
          }
        }
      }
  } else {
#pragma unroll
    for (int mi = 0; mi < 4; ++mi)
#pragma unroll
      for (int ni = 0; ni < 4; ++ni) {
        int nn = n0 + wn * 64 + ni * 16 + lr;
        float bv = bias[nn];
#pragma unroll
        for (int r = 0; r < 4; ++r) {
          int m = m0 + wm * 64 + mi * 16 + lc * 4 + r;
          f_out[(size_t)m * C_ + nn] = acc[mi][ni][r] + bv;
        }
      }
  }
}

// ---------------- flash attention v7: barrier-free, no LDS, frags direct to VGPR ----------------
// 768 blocks, all co-resident (0 LDS, <=168 VGPR -> 12 waves/CU). Static task map:
// xcd = bid&7 owns bh in [3*xcd, 3*xcd+3) (L2 affinity); zigzag qi balances per-CU load.
// Each wave owns 32 q rows, runs its own KV stream with NO barriers; the block's
// 4 waves share K/V tiles through L1. 16 dwordx4 loads per tile straight to regs.

#define PACK8(SV, O)                                                              \
  do {                                                                            \
    unsigned w0, w1, w2, w3, w4, w5, w6, w7;                                      \
    asm("v_cvt_pk_bf16_f32 %0, %1, %2" : "=v"(w0) : "v"(SV[0]), "v"(SV[1]));      \
    asm("v_cvt_pk_bf16_f32 %0, %1, %2" : "=v"(w1) : "v"(SV[2]), "v"(SV[3]));      \
    asm("v_cvt_pk_bf16_f32 %0, %1, %2" : "=v"(w2) : "v"(SV[4]), "v"(SV[5]));      \
    asm("v_cvt_pk_bf16_f32 %0, %1, %2" : "=v"(w3) : "v"(SV[6]), "v"(SV[7]));      \
    asm("v_cvt_pk_bf16_f32 %0, %1, %2" : "=v"(w4) : "v"(SV[8]), "v"(SV[9]));      \
    asm("v_cvt_pk_bf16_f32 %0, %1, %2" : "=v"(w5) : "v"(SV[10]), "v"(SV[11]));    \
    asm("v_cvt_pk_bf16_f32 %0, %1, %2" : "=v"(w6) : "v"(SV[12]), "v"(SV[13]));    \
    asm("v_cvt_pk_bf16_f32 %0, %1, %2" : "=v"(w7) : "v"(SV[14]), "v"(SV[15]));    \
    asm("v_permlane32_swap_b32 %0, %1" : "+v"(w0), "+v"(w2));                     \
    asm("v_permlane32_swap_b32 %0, %1" : "+v"(w1), "+v"(w3));                     \
    asm("v_permlane32_swap_b32 %0, %1" : "+v"(w4), "+v"(w6));                     \
    asm("v_permlane32_swap_b32 %0, %1" : "+v"(w5), "+v"(w7));                     \
    pw[(O) + 0] = w0; pw[(O) + 1] = w1; pw[(O) + 2] = w2; pw[(O) + 3] = w3;       \
    pw[(O) + 4] = w4; pw[(O) + 5] = w5; pw[(O) + 6] = w6; pw[(O) + 7] = w7;       \
  } while (0)

__global__ __launch_bounds__(256, 3) void flash7_k(const unsigned short* __restrict__ Qg,
                                                   const unsigned short* __restrict__ Kg,
                                                   const unsigned short* __restrict__ Vtg,
                                                   unsigned short* __restrict__ Og) {
  const int tid = threadIdx.x;
  const int wave = tid >> 6, lane = tid & 63;
  const int lq = lane & 31, hi = lane >> 5;

  const int bid = blockIdx.x;
  const int xcd = bid & 7, j = bid >> 3;
  const int g = j / 3, rb = j - g * 3;
  const int bh = xcd * 3 + rb;
  const int qi = (g & 1) ? (g >> 1) : (31 - (g >> 1));  // zigzag: CU-level load mix

  const int qw = qi * 128 + wave * 32;
  const int q_g = qw + lq;
  const int ntw = (qw >> 6) + 1;  // tiles this wave needs (qw%64 in {0,32})

  const size_t kbase = (size_t)bh * T_ * D_;
  const size_t vbase = (size_t)bh * D_ * T_;

  const unsigned short* qrow = Qg + kbase + (size_t)q_g * D_;
  bf16x8 qf[4];
#pragma unroll
  for (int t = 0; t < 4; ++t) qf[t] = *(const bf16x8*)(qrow + t * 16 + hi * 8);

  f32x16 accT0, accT1;
#pragma unroll
  for (int r = 0; r < 16; ++r) { accT0[r] = 0.f; accT1[r] = 0.f; }
  float lvec[8];
#pragma unroll
  for (int r = 0; r < 8; ++r) lvec[r] = 0.f;
  float m = 0.f;  // running max (relative); rescale triggers when tile max > m+8

  const unsigned short* kp0 = Kg + kbase + (size_t)lq * D_ + hi * 8;
  const unsigned short* vp0 = Vtg + vbase + (size_t)lq * T_ + hi * 8;

  for (int it = 0; it < ntw; ++it) {
    const int kv = it * 64;
    const unsigned short* kp = kp0 + (size_t)kv * D_;
    const unsigned short* vp = vp0 + kv;

    // ---- fragment loads straight to VGPRs (compiler inserts the waits) ----
    bf16x8 kf[8], vf[8];
#pragma unroll
    for (int t = 0; t < 4; ++t) {
      kf[2 * t]     = *(const bf16x8*)(kp + t * 16);
      kf[2 * t + 1] = *(const bf16x8*)(kp + 32 * D_ + t * 16);
      vf[2 * t]     = *(const bf16x8*)(vp + t * 16);
      vf[2 * t + 1] = *(const bf16x8*)(vp + (size_t)32 * T_ + t * 16);
    }

    // ---- S^T = K Q^T - m  (C-init = -m) ----
    const float negm = -m;
    f32x16 s0, s1;
#pragma unroll
    for (int r = 0; r < 16; ++r) { s0[r] = negm; s1[r] = negm; }
    __builtin_amdgcn_s_setprio(1);
#pragma unroll
    for (int t = 0; t < 4; ++t) {
      s0 = __builtin_amdgcn_mfma_f32_32x32x16_bf16(kf[2 * t], qf[t], s0, 0, 0, 0);
      s1 = __builtin_amdgcn_mfma_f32_32x32x16_bf16(kf[2 * t + 1], qf[t], s1, 0, 0, 0);
    }
    __builtin_amdgcn_s_setprio(0);

    // ---- causal mask (diagonal tiles only) ----
    if (kv + 63 > qw) {
#pragma unroll
      for (int r = 0; r < 16; ++r) {
        int key0 = kv + ((r & 3) + 8 * (r >> 2) + 4 * hi);
        if (key0 > q_g) s0[r] = -INFINITY;
        if (key0 + 32 > q_g) s1[r] = -INFINITY;
      }
    }

    // ---- relative max (tree) + defer-rescale ----
    float mx[16];
#pragma unroll
    for (int r = 0; r < 16; ++r) mx[r] = fmaxf(s0[r], s1[r]);
    float a0 = fmaxf(fmaxf(mx[0], mx[1]), mx[2]);
    float a1 = fmaxf(fmaxf(mx[3], mx[4]), mx[5]);
    float a2 = fmaxf(fmaxf(mx[6], mx[7]), mx[8]);
    float a3 = fmaxf(fmaxf(mx[9], mx[10]), mx[11]);
    float a4 = fmaxf(fmaxf(mx[12], mx[13]), mx[14]);
    float rx = fmaxf(fmaxf(fmaxf(a0, a1), fmaxf(a2, a3)), fmaxf(a4, mx[15]));
    rx = fmaxf(rx, __shfl_xor(rx, 32));

    if (!__all(rx <= 8.f)) {
      float dlt = fmaxf(rx, 0.f);
      float al = exp2_hw(-dlt);
      m += dlt;
#pragma unroll
      for (int r = 0; r < 16; ++r) { accT0[r] *= al; accT1[r] *= al; }
#pragma unroll
      for (int r = 0; r < 8; ++r) lvec[r] *= al;
#pragma unroll
      for (int r = 0; r < 16; ++r) { s0[r] -= dlt; s1[r] -= dlt; }
    }
#pragma unroll
    for (int r = 0; r < 16; ++r) s0[r] = exp2_hw(s0[r]);
#pragma unroll
    for (int r = 0; r < 16; ++r) s1[r] = exp2_hw(s1[r]);
#pragma unroll
    for (int r = 0; r < 8; ++r) lvec[r] += (s0[r] + s1[r]) + (s0[r + 8] + s1[r + 8]);

    // ---- P^T -> bf16 B-frags ----
    unsigned pw[16];
    PACK8(s0, 0);
    PACK8(s1, 8);

    // ---- O^T += Vt P^T ----
    __builtin_amdgcn_s_setprio(1);
#pragma unroll
    for (int ks = 0; ks < 4; ++ks) {
      union { unsigned u[4]; bf16x8 v; } pb;
      pb.u[0] = pw[ks * 4 + 0]; pb.u[1] = pw[ks * 4 + 1];
      pb.u[2] = pw[ks * 4 + 2]; pb.u[3] = pw[ks * 4 + 3];
      accT0 = __builtin_amdgcn_mfma_f32_32x32x16_bf16(vf[2 * ks], pb.v, accT0, 0, 0, 0);
      accT1 = __builtin_amdgcn_mfma_f32_32x32x16_bf16(vf[2 * ks + 1], pb.v, accT1, 0, 0, 0);
    }
    __builtin_amdgcn_s_setprio(0);
  }

  // ---- epilogue ----
  float l = 0.f;
#pragma unroll
  for (int r = 0; r < 8; ++r) l += lvec[r];
  l += __shfl_xor(l, 32);
  const float inv = 1.0f / l;
  const int b = bh / H_, h = bh - b * H_;
  unsigned short* orow = Og + ((size_t)b * T_ + q_g) * C_ + h * D_;
#pragma unroll
  for (int gg = 0; gg < 4; ++gg) {
    int d0 = 8 * gg + 4 * hi;
    float e0 = accT0[4 * gg + 0] * inv, e1 = accT0[4 * gg + 1] * inv;
    float e2 = accT0[4 * gg + 2] * inv, e3 = accT0[4 * gg + 3] * inv;
    float f0 = accT1[4 * gg + 0] * inv, f1 = accT1[4 * gg + 1] * inv;
    float f2 = accT1[4 * gg + 2] * inv, f3 = accT1[4 * gg + 3] * inv;
    uint2 ua, ub;
    asm("v_cvt_pk_bf16_f32 %0, %1, %2" : "=v"(ua.x) : "v"(e0), "v"(e1));
    asm("v_cvt_pk_bf16_f32 %0, %1, %2" : "=v"(ua.y) : "v"(e2), "v"(e3));
    asm("v_cvt_pk_bf16_f32 %0, %1, %2" : "=v"(ub.x) : "v"(f0), "v"(f1));
    asm("v_cvt_pk_bf16_f32 %0, %1, %2" : "=v"(ub.y) : "v"(f2), "v"(f3));
    *(uint2*)(orow + d0) = ua;
    *(uint2*)(orow + 32 + d0) = ub;
  }
}

// ---------------- launcher ----------------

extern "C" void kernel_launch(void* const* d_in, const int* in_sizes, int n_in,
                              void* d_out, int out_size, void* d_ws, size_t ws_size,
                              hipStream_t stream) {
  const float* x     = (const float*)d_in[0];
  const float* Wqkv  = (const float*)d_in[1];
  const float* Wproj = (const float*)d_in[2];
  const float* bproj = (const float*)d_in[3];
  float* out = (float*)d_out;

  char* ws = (char*)d_ws;
  unsigned short* xbf   = (unsigned short*)(ws);
  unsigned short* wqkvt = (unsigned short*)(ws + 12582912);
  unsigned short* wprjt = (unsigned short*)(ws + 16121856);
  unsigned short* Qb    = (unsigned short*)(ws + 17301504);
  unsigned short* Kb    = (unsigned short*)(ws + 29884416);
  unsigned short* Vtb   = (unsigned short*)(ws + 42467328);

  cast_bf16_k<<<6144, 256, 0, stream>>>(x, xbf, (B_ * T_ * C_) / 4);
  tpose_cast_k<<<dim3((3 * C_) / 64, C_ / 64), 256, 0, stream>>>(Wqkv, wqkvt, C_, 3 * C_);
  tpose_cast_k<<<dim3(C_ / 64, C_ / 64), 256, 0, stream>>>(Wproj, wprjt, C_, C_);

  gemm_k<0><<<(B_ * T_ / 128) * (3 * C_ / 128), 256, 0, stream>>>(
      xbf, wqkvt, C_, Qb, Kb, Vtb, nullptr, nullptr);

  flash7_k<<<768, 256, 0, stream>>>(Qb, Kb, Vtb, xbf);

  gemm_k<1><<<(B_ * T_ / 128) * (C_ / 128), 256, 0, stream>>>(
      xbf, wprjt, C_, nullptr, nullptr, nullptr, out, bproj);
}

// Round 8
// 200.607 us; speedup vs baseline: 1.6419x; 1.6419x over previous
//
#include <hip/hip_runtime.h>

#define B_ 2
#define T_ 4096
#define C_ 768
#define H_ 12
#define D_ 64
#define QTASK 96       /* tasks per XCD queue: 3 bh * 32 qi */

typedef __attribute__((ext_vector_type(8))) short bf16x8;
typedef __attribute__((ext_vector_type(4))) float f32x4;
typedef __attribute__((ext_vector_type(16))) float f32x16;

__device__ __forceinline__ unsigned short f2bf(float f) {
  union { float f; unsigned u; } v; v.f = f;
  unsigned r = v.u + 0x7fffu + ((v.u >> 16) & 1u);
  return (unsigned short)(r >> 16);
}

__device__ __forceinline__ float exp2_hw(float x) {
  float r;
  asm("v_exp_f32 %0, %1" : "=v"(r) : "v"(x));
  return r;
}

__device__ __forceinline__ void gll16(const void* g, void* l) {
  __builtin_amdgcn_global_load_lds((const __attribute__((address_space(1))) void*)g,
                                   (__attribute__((address_space(3))) void*)l, 16, 0, 0);
}

// ---------------- cast kernels ----------------

// f32 -> bf16 (coalesced); resets the 8 task-queue counters
__global__ __launch_bounds__(256) void cast_bf16_k(const float* __restrict__ in,
                                                   unsigned short* __restrict__ out, int n4,
                                                   unsigned* __restrict__ cnt) {
  int i = blockIdx.x * 256 + threadIdx.x;
  if (i < 128) cnt[i] = 0u;
  if (i >= n4) return;
  float4 v = ((const float4*)in)[i];
  union { unsigned short s[4]; unsigned long long u; } o;
  o.s[0] = f2bf(v.x); o.s[1] = f2bf(v.y); o.s[2] = f2bf(v.z); o.s[3] = f2bf(v.w);
  ((unsigned long long*)out)[i] = o.u;
}

// in [R][C] f32 -> out [C][R] bf16, 64x64 tiles via LDS (coalesced both sides)
__global__ __launch_bounds__(256) void tpose_cast_k(const float* __restrict__ in,
                                                    unsigned short* __restrict__ out,
                                                    int R, int C) {
  __shared__ unsigned short t[64][65];
  const int c0 = blockIdx.x * 64, r0 = blockIdx.y * 64;
  const int tr = threadIdx.x >> 6, tc = threadIdx.x & 63;
#pragma unroll
  for (int i = 0; i < 16; ++i) {
    int r = i * 4 + tr;
    t[r][tc] = f2bf(in[(size_t)(r0 + r) * C + c0 + tc]);
  }
  __syncthreads();
#pragma unroll
  for (int i = 0; i < 16; ++i) {
    int c = i * 4 + tr;
    out[(size_t)(c0 + c) * R + r0 + tc] = t[tc][c];
  }
}

// ---------------- GEMM (R5 structure, unchanged) ----------------

#define QSCALE 0.1803368801111243f /* 0.125 * log2(e) */

template <int MODE>
__global__ __launch_bounds__(256) void gemm_k(const unsigned short* __restrict__ A,
                                              const unsigned short* __restrict__ Bt,
                                              int K,
                                              unsigned short* __restrict__ q_out,
                                              unsigned short* __restrict__ k_out,
                                              unsigned short* __restrict__ vt_out,
                                              float* __restrict__ f_out,
                                              const float* __restrict__ bias) {
  __shared__ short a_lds[2][128 * 32];
  __shared__ short b_lds[2][128 * 32];
  const int tid = threadIdx.x;
  const int wave = tid >> 6, lane = tid & 63;
  const int wm = wave >> 1, wn = wave & 1;
  const int lr = lane & 15, lc = lane >> 4;

  const int id = blockIdx.x;
  const int xcd = id & 7, idc = id >> 3;
  const int bx = xcd * 8 + (idc & 7);
  const int by = idc >> 3;
  const int m0 = bx * 128, n0 = by * 128;

  f32x4 acc[4][4];
  for (int mi = 0; mi < 4; ++mi)
    for (int ni = 0; ni < 4; ++ni) acc[mi][ni] = (f32x4){0.f, 0.f, 0.f, 0.f};

  const unsigned short *ap[2], *bp[2];
  int lb[2];
#pragma unroll
  for (int p = 0; p < 2; ++p) {
    int chunk = p * 256 + wave * 64 + lane;
    int r = chunk >> 2, cc = chunk & 3;
    int c = cc ^ ((r >> 1) & 3);
    ap[p] = A + (size_t)(m0 + r) * K + c * 8;
    bp[p] = Bt + (size_t)(n0 + r) * K + c * 8;
    lb[p] = (p * 256 + wave * 64) * 8;
  }

  const int nks = K >> 5;
#pragma unroll
  for (int p = 0; p < 2; ++p) {
    gll16(ap[p], &a_lds[0][lb[p]]);
    gll16(bp[p], &b_lds[0][lb[p]]);
    ap[p] += 32; bp[p] += 32;
  }

  for (int ks = 0; ks < nks; ++ks) {
    const int buf = ks & 1;
    __builtin_amdgcn_s_barrier();
    __builtin_amdgcn_sched_barrier(0);
    if (ks + 1 < nks) {
#pragma unroll
      for (int p = 0; p < 2; ++p) {
        gll16(ap[p], &a_lds[buf ^ 1][lb[p]]);
        gll16(bp[p], &b_lds[buf ^ 1][lb[p]]);
        ap[p] += 32; bp[p] += 32;
      }
      asm volatile("s_waitcnt vmcnt(4)" ::: "memory");
    } else {
      asm volatile("s_waitcnt vmcnt(0)" ::: "memory");
    }
    __builtin_amdgcn_sched_barrier(0);
    __builtin_amdgcn_s_barrier();
    __builtin_amdgcn_sched_barrier(0);

    bf16x8 af[4], bfrag[4];
#pragma unroll
    for (int mi = 0; mi < 4; ++mi) {
      int r = wm * 64 + mi * 16 + lr;
      af[mi] = *(const bf16x8*)&a_lds[buf][r * 32 + (lc ^ ((r >> 1) & 3)) * 8];
    }
#pragma unroll
    for (int ni = 0; ni < 4; ++ni) {
      int r = wn * 64 + ni * 16 + lr;
      bfrag[ni] = *(const bf16x8*)&b_lds[buf][r * 32 + (lc ^ ((r >> 1) & 3)) * 8];
    }
    __builtin_amdgcn_s_setprio(1);
#pragma unroll
    for (int mi = 0; mi < 4; ++mi)
#pragma unroll
      for (int ni = 0; ni < 4; ++ni)
        acc[mi][ni] = __builtin_amdgcn_mfma_f32_16x16x32_bf16(af[mi], bfrag[ni], acc[mi][ni], 0, 0, 0);
    __builtin_amdgcn_s_setprio(0);
  }

  if (MODE == 0) {
    const int nn0 = n0 + wn * 64 + lr;
    const int which = n0 / 768;
#pragma unroll
    for (int mi = 0; mi < 4; ++mi)
#pragma unroll
      for (int ni = 0; ni < 4; ++ni) {
        int nn = nn0 + ni * 16;
        int rem = nn - which * 768;
        int h = rem >> 6, d = rem & 63;
        int t0v = m0 + wm * 64 + mi * 16 + lc * 4;
        int b = t0v >> 12, t = t0v & (T_ - 1);
        size_t bh = (size_t)(b * H_ + h);
        if (which == 2) {
          unsigned u0, u1;
          asm("v_cvt_pk_bf16_f32 %0, %1, %2" : "=v"(u0) : "v"(acc[mi][ni][0]), "v"(acc[mi][ni][1]));
          asm("v_cvt_pk_bf16_f32 %0, %1, %2" : "=v"(u1) : "v"(acc[mi][ni][2]), "v"(acc[mi][ni][3]));
          uint2 u = {u0, u1};
          *(uint2*)&vt_out[(bh * D_ + d) * T_ + t] = u;
        } else {
#pragma unroll
          for (int r = 0; r < 4; ++r) {
            float av = acc[mi][ni][r];
            if (which == 0) av *= QSCALE;
            unsigned short val = f2bf(av);
            if (which == 0) q_out[(bh * T_ + t + r) * D_ + d] = val;
            else            k_out[(bh * T_ + t + r) * D_ + d] = val;
          }
        }
      }
  } else {
#pragma unroll
    for (int mi = 0; mi < 4; ++mi)
#pragma unroll
      for (int ni = 0; ni < 4; ++ni) {
        int nn = n0 + wn * 64 + ni * 16 + lr;
        float bv = bias[nn];
#pragma unroll
        for (int r = 0; r < 4; ++r) {
          int m = m0 + wm * 64 + mi * 16 + lc * 4 + r;
          f_out[(size_t)m * C_ + nn] = acc[mi][ni][r] + bv;
        }
      }
  }
}

// ---------------- flash attention v8 ----------------
// Per-XCD dynamic queues: 64 workers vs 96 tasks per queue (LPT heavy-first) ->
// real dynamic feeding, no static tail. Depth-2 prefetch: 3 LDS buffer sets,
// stage(it+2) in flight, vmcnt(8)/(4)/(0). Frag-linear LDS (conflict-free).

#define PACK8(SV, O)                                                              \
  do {                                                                            \
    unsigned w0, w1, w2, w3, w4, w5, w6, w7;                                      \
    asm("v_cvt_pk_bf16_f32 %0, %1, %2" : "=v"(w0) : "v"(SV[0]), "v"(SV[1]));      \
    asm("v_cvt_pk_bf16_f32 %0, %1, %2" : "=v"(w1) : "v"(SV[2]), "v"(SV[3]));      \
    asm("v_cvt_pk_bf16_f32 %0, %1, %2" : "=v"(w2) : "v"(SV[4]), "v"(SV[5]));      \
    asm("v_cvt_pk_bf16_f32 %0, %1, %2" : "=v"(w3) : "v"(SV[6]), "v"(SV[7]));      \
    asm("v_cvt_pk_bf16_f32 %0, %1, %2" : "=v"(w4) : "v"(SV[8]), "v"(SV[9]));      \
    asm("v_cvt_pk_bf16_f32 %0, %1, %2" : "=v"(w5) : "v"(SV[10]), "v"(SV[11]));    \
    asm("v_cvt_pk_bf16_f32 %0, %1, %2" : "=v"(w6) : "v"(SV[12]), "v"(SV[13]));    \
    asm("v_cvt_pk_bf16_f32 %0, %1, %2" : "=v"(w7) : "v"(SV[14]), "v"(SV[15]));    \
    asm("v_permlane32_swap_b32 %0, %1" : "+v"(w0), "+v"(w2));                     \
    asm("v_permlane32_swap_b32 %0, %1" : "+v"(w1), "+v"(w3));                     \
    asm("v_permlane32_swap_b32 %0, %1" : "+v"(w4), "+v"(w6));                     \
    asm("v_permlane32_swap_b32 %0, %1" : "+v"(w5), "+v"(w7));                     \
    pw[(O) + 0] = w0; pw[(O) + 1] = w1; pw[(O) + 2] = w2; pw[(O) + 3] = w3;       \
    pw[(O) + 4] = w4; pw[(O) + 5] = w5; pw[(O) + 6] = w6; pw[(O) + 7] = w7;       \
  } while (0)

__global__ __launch_bounds__(256) void flash8_k(const unsigned short* __restrict__ Qg,
                                                const unsigned short* __restrict__ Kg,
                                                const unsigned short* __restrict__ Vtg,
                                                unsigned short* __restrict__ Og,
                                                unsigned* __restrict__ cnt) {
  __shared__ short k_lds[3][8 * 512];
  __shared__ short vt_lds[3][8 * 512];
  __shared__ int task_s;

  const int tid = threadIdx.x;
  const int wave = tid >> 6, lane = tid & 63;
  const int lq = lane & 31, hi = lane >> 5;
  const int xq = blockIdx.x & 7;
  unsigned* myq = cnt + xq * 16;

  for (;;) {
    if (tid == 0) task_s = (int)atomicAdd(myq, 1u);
    __syncthreads();
    const int task = task_s;
    if (task >= QTASK) return;

    const int qi = 31 - task / 3;       // LPT: heavy first
    const int bh = xq * 3 + (task - (task / 3) * 3);
    const int qw = qi * 128 + wave * 32;
    const int q_g = qw + lq;

    const size_t kbase = (size_t)bh * T_ * D_;
    const size_t vbase = (size_t)bh * D_ * T_;

    const unsigned short* qrow = Qg + kbase + (size_t)q_g * D_;
    bf16x8 qf[4];
#pragma unroll
    for (int t = 0; t < 4; ++t) qf[t] = *(const bf16x8*)(qrow + t * 16 + hi * 8);

    f32x16 accT0, accT1;
#pragma unroll
    for (int r = 0; r < 16; ++r) { accT0[r] = 0.f; accT1[r] = 0.f; }
    float lvec[8];
#pragma unroll
    for (int r = 0; r < 8; ++r) lvec[r] = 0.f;
    float m = 0.f;

    const int ntl = 2 * qi + 2;

    const unsigned short* kp0 = Kg + kbase + (size_t)((wave & 1) * 32 + lq) * D_ +
                                (wave >> 1) * 16 + hi * 8;
    const unsigned short* vp0 = Vtg + vbase + (size_t)((wave & 1) * 32 + lq) * T_ +
                                (wave >> 1) * 16 + hi * 8;
    const int lb0 = wave * 512, lb1 = (wave + 4) * 512;

    auto stage = [&](int it, int sb) {
      const unsigned short* kp = kp0 + (size_t)it * 64 * D_;
      const unsigned short* vp = vp0 + it * 64;
      gll16(kp, &k_lds[sb][lb0]); gll16(kp + 32, &k_lds[sb][lb1]);
      gll16(vp, &vt_lds[sb][lb0]); gll16(vp + 32, &vt_lds[sb][lb1]);
    };

    stage(0, 0);
    stage(1, 1);  // ntl >= 2 always

    int buf = 0;
    for (int j = 0; j < ntl; ++j) {
      const int kv = j * 64;

      __builtin_amdgcn_s_barrier();       // all waves done compute(j-1): buf[(j+2)%3] reusable
      __builtin_amdgcn_sched_barrier(0);
      if (j + 2 < ntl) {
        int tb = buf + 2; if (tb >= 3) tb -= 3;
        stage(j + 2, tb);
        asm volatile("s_waitcnt vmcnt(8)" ::: "memory");   // stage(j) landed
      } else if (j + 1 < ntl) {
        asm volatile("s_waitcnt vmcnt(4)" ::: "memory");
      } else {
        asm volatile("s_waitcnt vmcnt(0)" ::: "memory");
      }
      __builtin_amdgcn_sched_barrier(0);
      __builtin_amdgcn_s_barrier();       // buf[j%3] ready for everyone
      __builtin_amdgcn_sched_barrier(0);

      if (kv <= qw + 31) {
        const float negm = -m;
        f32x16 s0, s1;
#pragma unroll
        for (int r = 0; r < 16; ++r) { s0[r] = negm; s1[r] = negm; }
        __builtin_amdgcn_s_setprio(1);
#pragma unroll
        for (int t = 0; t < 4; ++t) {
          bf16x8 kf0 = *(const bf16x8*)&k_lds[buf][(t * 2 + 0) * 512 + lane * 8];
          bf16x8 kf1 = *(const bf16x8*)&k_lds[buf][(t * 2 + 1) * 512 + lane * 8];
          s0 = __builtin_amdgcn_mfma_f32_32x32x16_bf16(kf0, qf[t], s0, 0, 0, 0);
          s1 = __builtin_amdgcn_mfma_f32_32x32x16_bf16(kf1, qf[t], s1, 0, 0, 0);
        }
        __builtin_amdgcn_s_setprio(0);

        if (kv + 63 > qw) {
#pragma unroll
          for (int r = 0; r < 16; ++r) {
            int key0 = kv + ((r & 3) + 8 * (r >> 2) + 4 * hi);
            if (key0 > q_g) s0[r] = -INFINITY;
            if (key0 + 32 > q_g) s1[r] = -INFINITY;
          }
        }

        float mx[16];
#pragma unroll
        for (int r = 0; r < 16; ++r) mx[r] = fmaxf(s0[r], s1[r]);
        float a0 = fmaxf(fmaxf(mx[0], mx[1]), mx[2]);
        float a1 = fmaxf(fmaxf(mx[3], mx[4]), mx[5]);
        float a2 = fmaxf(fmaxf(mx[6], mx[7]), mx[8]);
        float a3 = fmaxf(fmaxf(mx[9], mx[10]), mx[11]);
        float a4 = fmaxf(fmaxf(mx[12], mx[13]), mx[14]);
        float rx = fmaxf(fmaxf(fmaxf(a0, a1), fmaxf(a2, a3)), fmaxf(a4, mx[15]));
        rx = fmaxf(rx, __shfl_xor(rx, 32));

        if (!__all(rx <= 8.f)) {
          float dlt = fmaxf(rx, 0.f);
          float al = exp2_hw(-dlt);
          m += dlt;
#pragma unroll
          for (int r = 0; r < 16; ++r) { accT0[r] *= al; accT1[r] *= al; }
#pragma unroll
          for (int r = 0; r < 8; ++r) lvec[r] *= al;
#pragma unroll
          for (int r = 0; r < 16; ++r) { s0[r] -= dlt; s1[r] -= dlt; }
        }
#pragma unroll
        for (int r = 0; r < 16; ++r) s0[r] = exp2_hw(s0[r]);
#pragma unroll
        for (int r = 0; r < 16; ++r) s1[r] = exp2_hw(s1[r]);
#pragma unroll
        for (int r = 0; r < 8; ++r) lvec[r] += (s0[r] + s1[r]) + (s0[r + 8] + s1[r + 8]);

        unsigned pw[16];
        PACK8(s0, 0);
        PACK8(s1, 8);

        __builtin_amdgcn_s_setprio(1);
#pragma unroll
        for (int ks = 0; ks < 4; ++ks) {
          union { unsigned u[4]; bf16x8 v; } pb;
          pb.u[0] = pw[ks * 4 + 0]; pb.u[1] = pw[ks * 4 + 1];
          pb.u[2] = pw[ks * 4 + 2]; pb.u[3] = pw[ks * 4 + 3];
          bf16x8 vf0 = *(const bf16x8*)&vt_lds[buf][(ks * 2 + 0) * 512 + lane * 8];
          bf16x8 vf1 = *(const bf16x8*)&vt_lds[buf][(ks * 2 + 1) * 512 + lane * 8];
          accT0 = __builtin_amdgcn_mfma_f32_32x32x16_bf16(vf0, pb.v, accT0, 0, 0, 0);
          accT1 = __builtin_amdgcn_mfma_f32_32x32x16_bf16(vf1, pb.v, accT1, 0, 0, 0);
        }
        __builtin_amdgcn_s_setprio(0);
      }
      ++buf; if (buf >= 3) buf = 0;
    }

    // ---- final l reduce + epilogue ----
    float l = 0.f;
#pragma unroll
    for (int r = 0; r < 8; ++r) l += lvec[r];
    l += __shfl_xor(l, 32);
    const float inv = 1.0f / l;
    const int b = bh / H_, h = bh - b * H_;
    unsigned short* orow = Og + ((size_t)b * T_ + q_g) * C_ + h * D_;
#pragma unroll
    for (int g = 0; g < 4; ++g) {
      int d0 = 8 * g + 4 * hi;
      float e0 = accT0[4 * g + 0] * inv, e1 = accT0[4 * g + 1] * inv;
      float e2 = accT0[4 * g + 2] * inv, e3 = accT0[4 * g + 3] * inv;
      float f0 = accT1[4 * g + 0] * inv, f1 = accT1[4 * g + 1] * inv;
      float f2 = accT1[4 * g + 2] * inv, f3 = accT1[4 * g + 3] * inv;
      uint2 ua, ub;
      asm("v_cvt_pk_bf16_f32 %0, %1, %2" : "=v"(ua.x) : "v"(e0), "v"(e1));
      asm("v_cvt_pk_bf16_f32 %0, %1, %2" : "=v"(ua.y) : "v"(e2), "v"(e3));
      asm("v_cvt_pk_bf16_f32 %0, %1, %2" : "=v"(ub.x) : "v"(f0), "v"(f1));
      asm("v_cvt_pk_bf16_f32 %0, %1, %2" : "=v"(ub.y) : "v"(f2), "v"(f3));
      *(uint2*)(orow + d0) = ua;
      *(uint2*)(orow + 32 + d0) = ub;
    }
    __syncthreads();  // quiesce LDS before next pop
  }
}

// ---------------- launcher ----------------

extern "C" void kernel_launch(void* const* d_in, const int* in_sizes, int n_in,
                              void* d_out, int out_size, void* d_ws, size_t ws_size,
                              hipStream_t stream) {
  const float* x     = (const float*)d_in[0];
  const float* Wqkv  = (const float*)d_in[1];
  const float* Wproj = (const float*)d_in[2];
  const float* bproj = (const float*)d_in[3];
  float* out = (float*)d_out;

  char* ws = (char*)d_ws;
  unsigned short* xbf   = (unsigned short*)(ws);
  unsigned short* wqkvt = (unsigned short*)(ws + 12582912);
  unsigned short* wprjt = (unsigned short*)(ws + 16121856);
  unsigned short* Qb    = (unsigned short*)(ws + 17301504);
  unsigned short* Kb    = (unsigned short*)(ws + 29884416);
  unsigned short* Vtb   = (unsigned short*)(ws + 42467328);
  unsigned*       cnt   = (unsigned*)(ws + 55050240);  // 128 u32

  cast_bf16_k<<<6144, 256, 0, stream>>>(x, xbf, (B_ * T_ * C_) / 4, cnt);
  tpose_cast_k<<<dim3((3 * C_) / 64, C_ / 64), 256, 0, stream>>>(Wqkv, wqkvt, C_, 3 * C_);
  tpose_cast_k<<<dim3(C_ / 64, C_ / 64), 256, 0, stream>>>(Wproj, wprjt, C_, C_);

  gemm_k<0><<<(B_ * T_ / 128) * (3 * C_ / 128), 256, 0, stream>>>(
      xbf, wqkvt, C_, Qb, Kb, Vtb, nullptr, nullptr);

  flash8_k<<<512, 256, 0, stream>>>(Qb, Kb, Vtb, xbf, cnt);

  gemm_k<1><<<(B_ * T_ / 128) * (C_ / 128), 256, 0, stream>>>(
      xbf, wprjt, C_, nullptr, nullptr, nullptr, out, bproj);
}